// Round 1
// baseline (541.896 us; speedup 1.0000x reference)
//
#include <hip/hip_runtime.h>

// MQA: B=2, S=2048, D=2048, H=16, HD=128.  All GEMMs bf16 MFMA 16x16x32,
// fp32 accumulation. gemm_bt structure (m97): A[m][k], BT[n][k], 128x128 tile,
// BK=32, global_load_lds width 16, XOR chunk swizzle for LDS bank spread.

typedef unsigned short u16;
typedef __attribute__((ext_vector_type(8))) short bf16x8;   // 8 bf16 = 4 VGPR
typedef __attribute__((ext_vector_type(4))) float f32x4;

#define D_MODEL 2048
#define SEQ     2048
#define NH      16
#define HD      128
#define MROWS   4096   // B*S
#define BK      32

__device__ __forceinline__ u16 f2bf(float f){
  union { float f; unsigned u; } v; v.f = f;
  unsigned r = (v.u + 0x7FFFu + ((v.u >> 16) & 1u)) >> 16;  // RNE
  return (u16)r;
}

__device__ __forceinline__ void gll16(const void* g, void* l){
  __builtin_amdgcn_global_load_lds(
      (const __attribute__((address_space(1))) void*)g,
      (__attribute__((address_space(3))) void*)l, 16, 0, 0);
}

// ---------------- fp32 -> bf16 conversion of q,k,v ----------------
__global__ __launch_bounds__(256) void convert3_kernel(
    const float4* __restrict__ a, const float4* __restrict__ b, const float4* __restrict__ c,
    ushort4* __restrict__ oa, ushort4* __restrict__ ob, ushort4* __restrict__ oc){
  int i = blockIdx.x*256 + threadIdx.x;        // 2,097,152 threads * 4 elems
  float4 va = a[i], vb = b[i], vc = c[i];
  ushort4 ra, rb, rc;
  ra.x=f2bf(va.x); ra.y=f2bf(va.y); ra.z=f2bf(va.z); ra.w=f2bf(va.w);
  rb.x=f2bf(vb.x); rb.y=f2bf(vb.y); rb.z=f2bf(vb.z); rb.w=f2bf(vb.w);
  rc.x=f2bf(vc.x); rc.y=f2bf(vc.y); rc.z=f2bf(vc.z); rc.w=f2bf(vc.w);
  oa[i]=ra; ob[i]=rb; oc[i]=rc;
}

// ---------------- transpose + convert: W[R][C] fp32 -> WT[C][R] bf16 ----------------
__global__ __launch_bounds__(256) void transpose_kernel(
    const float* __restrict__ in, u16* __restrict__ out, int R, int C){
  __shared__ float t[32][33];
  int c0 = blockIdx.x*32, r0 = blockIdx.y*32;
  int tx = threadIdx.x, ty = threadIdx.y;      // block (32,8)
  #pragma unroll
  for (int k=0;k<4;k++) t[ty+k*8][tx] = in[(size_t)(r0+ty+k*8)*C + c0+tx];
  __syncthreads();
  #pragma unroll
  for (int k=0;k<4;k++) out[(size_t)(c0+ty+k*8)*R + r0+tx] = f2bf(t[tx][ty+k*8]);
}

// ---------------- shared GEMM core: C += A(128 rows) x BT(128 rows)^T over [kbeg,kend) ----------------
// LDS chunk swizzle: row of 4 chunks(8 bf16 each); chunk at position p holds global
// chunk p ^ ((row>>1)&3)  -> 2-way max bank aliasing on b128 frag reads (free).
__device__ __forceinline__ void gemm_core(
    const u16* __restrict__ A, const u16* __restrict__ BT,
    int lda, int ldb, int m0, int n0, int kbeg, int kend,
    u16* As, u16* Bs, f32x4 acc[4][4])
{
  const int t = threadIdx.x;
  const int w = t >> 6, l = t & 63;
  const int wr = w >> 1, wc = w & 1;
  const int c16 = l & 15, q = l >> 4;
  const int srow = l >> 2;                         // 0..15 within wave's 16-row slab
  const int sc   = ((l & 3) ^ ((l >> 3) & 3)) * 8; // swizzled global k-offset (elems)

  int aoff[4], boff[4];
  #pragma unroll
  for (int mt=0;mt<4;mt++){
    int row = wr*64 + mt*16 + c16;
    aoff[mt] = row*BK + ((q ^ ((row>>1)&3))*8);
  }
  #pragma unroll
  for (int nt=0;nt<4;nt++){
    int row = wc*64 + nt*16 + c16;
    boff[nt] = row*BK + ((q ^ ((row>>1)&3))*8);
  }

  for (int k0 = kbeg; k0 < kend; k0 += BK){
    #pragma unroll
    for (int half=0; half<2; half++){
      int r = half*64 + w*16 + srow;
      gll16(A  + (size_t)(m0+r)*lda + k0 + sc, As + (half*64 + w*16)*BK);
      gll16(BT + (size_t)(n0+r)*ldb + k0 + sc, Bs + (half*64 + w*16)*BK);
    }
    __syncthreads();                               // drains vmcnt for GLL
    bf16x8 af[4], bfr[4];
    #pragma unroll
    for (int mt=0;mt<4;mt++) af[mt]  = *(const bf16x8*)(As + aoff[mt]);
    #pragma unroll
    for (int nt=0;nt<4;nt++) bfr[nt] = *(const bf16x8*)(Bs + boff[nt]);
    #pragma unroll
    for (int mt=0;mt<4;mt++)
      #pragma unroll
      for (int nt=0;nt<4;nt++)
        acc[mt][nt] = __builtin_amdgcn_mfma_f32_16x16x32_bf16(af[mt], bfr[nt], acc[mt][nt], 0,0,0);
    __syncthreads();
  }
}

// ---------------- GEMM + bias, bf16 or fp32 output ----------------
template<bool BF16OUT>
__global__ __launch_bounds__(256) void gemm_bias(
    const u16* __restrict__ A, const u16* __restrict__ BT, const float* __restrict__ bias,
    void* __restrict__ C, int lda, int ldb, int ldc, int K)
{
  __shared__ u16 As[128*BK], Bs[128*BK];
  f32x4 acc[4][4];
  f32x4 z = {0.f,0.f,0.f,0.f};
  #pragma unroll
  for (int i=0;i<4;i++) for (int j=0;j<4;j++) acc[i][j] = z;
  int m0 = blockIdx.x*128, n0 = blockIdx.y*128;
  gemm_core(A, BT, lda, ldb, m0, n0, 0, K, As, Bs, acc);
  const int t = threadIdx.x, w = t>>6, l = t&63, wr = w>>1, wc = w&1, c16 = l&15, q = l>>4;
  #pragma unroll
  for (int mt=0;mt<4;mt++)
    #pragma unroll
    for (int nt=0;nt<4;nt++){
      int col = n0 + wc*64 + nt*16 + c16;
      float bv = bias[col];
      #pragma unroll
      for (int r=0;r<4;r++){
        int row = m0 + wr*64 + mt*16 + q*4 + r;
        float v = acc[mt][nt][r] + bv;
        if (BF16OUT) ((u16*)C)[(size_t)row*ldc + col] = f2bf(v);
        else         ((float*)C)[(size_t)row*ldc + col] = v;
      }
    }
}

// ---------------- fused K/V projection, split-K=4, fp32 partials ----------------
__global__ __launch_bounds__(256) void kvproj_kernel(
    const u16* __restrict__ kb, const u16* __restrict__ vb,
    const u16* __restrict__ WkT, const u16* __restrict__ WvT, float* __restrict__ part)
{
  __shared__ u16 As[128*BK], Bs[128*BK];
  f32x4 acc[4][4];
  f32x4 z = {0.f,0.f,0.f,0.f};
  #pragma unroll
  for (int i=0;i<4;i++) for (int j=0;j<4;j++) acc[i][j] = z;
  int m0 = blockIdx.x*128;
  int nb = blockIdx.y;                 // 0 = K, 1 = V
  int zi = blockIdx.z;                 // 0..3 split-K
  const u16* A  = nb ? vb  : kb;
  const u16* BT = nb ? WvT : WkT;
  gemm_core(A, BT, D_MODEL, D_MODEL, m0, 0, zi*512, zi*512 + 512, As, Bs, acc);
  float* dst = part + (size_t)(zi*2 + nb)*524288;   // [z][nb][4096][128]
  const int t = threadIdx.x, w = t>>6, l = t&63, wr = w>>1, wc = w&1, c16 = l&15, q = l>>4;
  #pragma unroll
  for (int mt=0;mt<4;mt++)
    #pragma unroll
    for (int nt=0;nt<4;nt++){
      int col = wc*64 + nt*16 + c16;
      #pragma unroll
      for (int r=0;r<4;r++){
        int row = m0 + wr*64 + mt*16 + q*4 + r;
        dst[(size_t)row*128 + col] = acc[mt][nt][r];
      }
    }
}

// ---------------- reduce split-K partials; emit Kp bf16 [4096][128] and VpT bf16 [B][128][S] ----------------
__global__ __launch_bounds__(256) void kv_reduce_kernel(
    const float* __restrict__ part, const float* __restrict__ bk, const float* __restrict__ bv,
    u16* __restrict__ Kp, u16* __restrict__ VpT){
  int idx = blockIdx.x*256 + threadIdx.x;          // 0..524287
  int d = idx & 127, sg = idx >> 7;
  float ka = 0.f, va = 0.f;
  #pragma unroll
  for (int zi=0; zi<4; zi++){
    ka += part[(size_t)(zi*2+0)*524288 + idx];
    va += part[(size_t)(zi*2+1)*524288 + idx];
  }
  Kp[idx] = f2bf(ka + bk[d]);
  int b = sg >> 11, sl = sg & 2047;
  VpT[(size_t)b*262144 + (size_t)d*2048 + sl] = f2bf(va + bv[d]);
}

// ---------------- flash attention: Q-tile 128 rows, K-tile 64 keys ----------------
// wave owns 32 complete q rows -> softmax stats wave-local (16-lane shuffle reduce).
// LDS 51.2 KB: Ks 16K | Vs(V^T) 16K | Ps 4x4.5K (padded 72 -> b128 reads 2-way).
__global__ __launch_bounds__(256) void attn_kernel(
    const u16* __restrict__ Qp, const u16* __restrict__ Kp,
    const u16* __restrict__ VpT, u16* __restrict__ attnb){
  __shared__ u16 lds[8192 + 8192 + 4*2304];
  const int t = threadIdx.x;
  const int w = t >> 6, l = t & 63;
  const int c16 = l & 15, q = l >> 4;
  u16* Ks = lds;
  u16* Vs = lds + 8192;
  u16* Ps = lds + 16384 + w*2304;

  const int qt = blockIdx.x;           // 0..15
  const int bh = blockIdx.y;           // 0..31
  const int b = bh >> 4, h = bh & 15;

  const u16* Qbase = Qp  + ((size_t)(b*SEQ + qt*128))*D_MODEL + h*HD;
  const u16* Kbase = Kp  + (size_t)(b*SEQ)*HD;
  const u16* Vbase = VpT + (size_t)b*HD*SEQ;

  // stage this wave's 32 Q rows into scratch (Ks|Vs space), row swizzle key = r&15
  {
    u16* qtmp = lds + w*4096;
    #pragma unroll
    for (int j=0;j<8;j++){
      int r = j*4 + (l >> 4);                     // 0..31
      int cpos = ((l & 15) ^ (r & 15)) * 8;
      gll16(Qbase + (size_t)(w*32 + r)*D_MODEL + cpos, qtmp + j*512);
    }
  }
  __syncthreads();
  bf16x8 qf[2][4];
  #pragma unroll
  for (int mt=0;mt<2;mt++)
    #pragma unroll
    for (int kk=0;kk<4;kk++){
      int ch = kk*4 + q;
      qf[mt][kk] = *(const bf16x8*)(lds + w*4096 + (mt*16 + c16)*128 + ((ch ^ c16) & 15)*8);
    }
  __syncthreads();   // all waves done reading Q before K/V staging overwrites

  f32x4 o[2][8];
  f32x4 z4 = {0.f,0.f,0.f,0.f};
  #pragma unroll
  for (int mt=0;mt<2;mt++) for (int nt=0;nt<8;nt++) o[mt][nt] = z4;
  float mrow[2][4], lrow[2][4];
  #pragma unroll
  for (int mt=0;mt<2;mt++) for (int r=0;r<4;r++){ mrow[mt][r] = -1e30f; lrow[mt][r] = 0.f; }
  const float cs = 0.08838834764831845f * 1.4426950408889634f;  // (1/sqrt(128))*log2(e)

  for (int kt = 0; kt < 32; kt++){
    // stage K tile: 64 keys x 128d, swizzle key r&15
    #pragma unroll
    for (int j=0;j<4;j++){
      int r = j*16 + w*4 + (l >> 4);              // 0..63
      int cpos = ((l & 15) ^ (r & 15)) * 8;
      gll16(Kbase + (size_t)(kt*64 + r)*HD + cpos, Ks + (j*16 + w*4)*128);
    }
    // stage V^T tile: 128d x 64 keys, swizzle key r&7
    #pragma unroll
    for (int j=0;j<4;j++){
      int r = j*32 + w*8 + (l >> 3);              // 0..127
      int cpos = ((l & 7) ^ (r & 7)) * 8;
      gll16(Vbase + (size_t)r*SEQ + kt*64 + cpos, Vs + (j*32 + w*8)*64);
    }
    __syncthreads();

    // S = Q K^T  (raw, unscaled)
    f32x4 s[2][4];
    #pragma unroll
    for (int mt=0;mt<2;mt++) for (int nt=0;nt<4;nt++) s[mt][nt] = z4;
    #pragma unroll
    for (int kk=0;kk<4;kk++){
      #pragma unroll
      for (int nt=0;nt<4;nt++){
        int row = nt*16 + c16;
        int ch = kk*4 + q;
        bf16x8 bfr = *(const bf16x8*)(Ks + row*128 + ((ch ^ c16) & 15)*8);
        s[0][nt] = __builtin_amdgcn_mfma_f32_16x16x32_bf16(qf[0][kk], bfr, s[0][nt], 0,0,0);
        s[1][nt] = __builtin_amdgcn_mfma_f32_16x16x32_bf16(qf[1][kk], bfr, s[1][nt], 0,0,0);
      }
    }

    // online softmax, per-row (rows live in quads; reduce over lanes 0..15 of group)
    float al[2][4];
    #pragma unroll
    for (int mt=0;mt<2;mt++)
      #pragma unroll
      for (int r=0;r<4;r++){
        float vmax = s[mt][0][r];
        #pragma unroll
        for (int nt=1;nt<4;nt++) vmax = fmaxf(vmax, s[mt][nt][r]);
        vmax = fmaxf(vmax, __shfl_xor(vmax, 1));
        vmax = fmaxf(vmax, __shfl_xor(vmax, 2));
        vmax = fmaxf(vmax, __shfl_xor(vmax, 4));
        vmax = fmaxf(vmax, __shfl_xor(vmax, 8));
        float mold = mrow[mt][r];
        float mnew = fmaxf(mold, vmax);
        float a = exp2f((mold - mnew)*cs);
        mrow[mt][r] = mnew; al[mt][r] = a;
        float rsum = 0.f;
        #pragma unroll
        for (int nt=0;nt<4;nt++){
          float p = exp2f((s[mt][nt][r] - mnew)*cs);
          s[mt][nt][r] = p; rsum += p;
        }
        rsum += __shfl_xor(rsum, 1);
        rsum += __shfl_xor(rsum, 2);
        rsum += __shfl_xor(rsum, 4);
        rsum += __shfl_xor(rsum, 8);
        lrow[mt][r] = lrow[mt][r]*a + rsum;
      }
    #pragma unroll
    for (int mt=0;mt<2;mt++)
      #pragma unroll
      for (int nt=0;nt<8;nt++)
        #pragma unroll
        for (int r=0;r<4;r++) o[mt][nt][r] *= al[mt][r];

    // P -> LDS (C-layout write), padded row 72 for 2-way A-frag reads
    #pragma unroll
    for (int mt=0;mt<2;mt++)
      #pragma unroll
      for (int nt=0;nt<4;nt++)
        #pragma unroll
        for (int r=0;r<4;r++)
          Ps[(mt*16 + q*4 + r)*72 + nt*16 + c16] = f2bf(s[mt][nt][r]);
    __syncthreads();

    // O += P V  (A from Ps, B from V^T)
    #pragma unroll
    for (int kk=0;kk<2;kk++){
      bf16x8 af0 = *(const bf16x8*)(Ps + (size_t)( c16     )*72 + kk*32 + q*8);
      bf16x8 af1 = *(const bf16x8*)(Ps + (size_t)(16 + c16 )*72 + kk*32 + q*8);
      #pragma unroll
      for (int nt=0;nt<8;nt++){
        int row = nt*16 + c16;
        int ch = kk*4 + q;
        bf16x8 bfr = *(const bf16x8*)(Vs + row*64 + ((ch ^ (c16 & 7)))*8);
        o[0][nt] = __builtin_amdgcn_mfma_f32_16x16x32_bf16(af0, bfr, o[0][nt], 0,0,0);
        o[1][nt] = __builtin_amdgcn_mfma_f32_16x16x32_bf16(af1, bfr, o[1][nt], 0,0,0);
      }
    }
    __syncthreads();
  }

  // normalize + write attn output (bf16, [b][s][h*128+d])
  #pragma unroll
  for (int mt=0;mt<2;mt++){
    float inv[4];
    #pragma unroll
    for (int r=0;r<4;r++) inv[r] = 1.f / lrow[mt][r];
    #pragma unroll
    for (int nt=0;nt<8;nt++)
      #pragma unroll
      for (int r=0;r<4;r++){
        int row = qt*128 + w*32 + mt*16 + q*4 + r;
        int col = h*HD + nt*16 + c16;
        attnb[((size_t)b*SEQ + row)*D_MODEL + col] = f2bf(o[mt][nt][r] * inv[r]);
      }
  }
}

extern "C" void kernel_launch(void* const* d_in, const int* in_sizes, int n_in,
                              void* d_out, int out_size, void* d_ws, size_t ws_size,
                              hipStream_t stream) {
  (void)in_sizes; (void)n_in; (void)out_size; (void)ws_size;
  const float* query = (const float*)d_in[0];
  const float* key   = (const float*)d_in[1];
  const float* value = (const float*)d_in[2];
  const float* Wq    = (const float*)d_in[3];
  const float* bq    = (const float*)d_in[4];
  const float* Wk    = (const float*)d_in[5];
  const float* bk    = (const float*)d_in[6];
  const float* Wv    = (const float*)d_in[7];
  const float* bv    = (const float*)d_in[8];
  const float* Wo    = (const float*)d_in[9];
  const float* bo    = (const float*)d_in[10];
  float* out = (float*)d_out;

  // workspace layout (bytes; all offsets 16B-aligned)
  char* W = (char*)d_ws;
  u16*  qb     = (u16*) (W + 0);          // 16 MB  bf16 query [4096][2048]
  u16*  kb     = (u16*) (W + 16777216);   // 16 MB  bf16 key
  u16*  vb     = (u16*) (W + 33554432);   // 16 MB  bf16 value
  u16*  WqT    = (u16*) (W + 50331648);   //  8 MB  Wq^T  [2048][2048]
  u16*  WoT    = (u16*) (W + 58720256);   //  8 MB  Wo^T
  u16*  WkT    = (u16*) (W + 67108864);   // .5 MB  Wk^T  [128][2048]
  u16*  WvT    = (u16*) (W + 67633152);   // .5 MB  Wv^T
  u16*  Qp     = (u16*) (W + 68157440);   // 16 MB  Q proj bf16 [4096][2048]
  u16*  Kp     = (u16*) (W + 84934656);   //  1 MB  K proj bf16 [4096][128]
  u16*  VpT    = (u16*) (W + 85983232);   //  1 MB  V proj^T bf16 [B][128][2048]
  u16*  attnb  = (u16*) (W + 87031808);   // 16 MB  attention out bf16 [4096][2048]
  float* kvpart= (float*)(W + 103809024); // 16 MB  split-K partials [4][2][4096][128]

  convert3_kernel<<<8192, 256, 0, stream>>>(
      (const float4*)query, (const float4*)key, (const float4*)value,
      (ushort4*)qb, (ushort4*)kb, (ushort4*)vb);
  transpose_kernel<<<dim3(64,64), dim3(32,8), 0, stream>>>(Wq, WqT, 2048, 2048);
  transpose_kernel<<<dim3(64,64), dim3(32,8), 0, stream>>>(Wo, WoT, 2048, 2048);
  transpose_kernel<<<dim3(4,64),  dim3(32,8), 0, stream>>>(Wk, WkT, 2048, 128);
  transpose_kernel<<<dim3(4,64),  dim3(32,8), 0, stream>>>(Wv, WvT, 2048, 128);

  gemm_bias<true><<<dim3(32,16), 256, 0, stream>>>(qb, WqT, bq, Qp, 2048, 2048, 2048, 2048);
  kvproj_kernel<<<dim3(32,2,4), 256, 0, stream>>>(kb, vb, WkT, WvT, kvpart);
  kv_reduce_kernel<<<2048, 256, 0, stream>>>(kvpart, bk, bv, Kp, VpT);
  attn_kernel<<<dim3(16,32), 256, 0, stream>>>(Qp, Kp, VpT, attnb);
  gemm_bias<false><<<dim3(32,16), 256, 0, stream>>>(attnb, WoT, bo, out, 2048, 2048, 2048, 2048);
}

// Round 2
// 490.348 us; speedup vs baseline: 1.1051x; 1.1051x over previous
//
#include <hip/hip_runtime.h>

// MQA: B=2, S=2048, D=2048, H=16, HD=128.  GEMMs bf16 MFMA 16x16x32, fp32 acc.
// Attention: S^T trick — QK^T computed as mfma(K,Q) so softmax keys are in-lane
// and P lands directly in the 16x16x16 PV B-operand layout (no LDS round-trip).

typedef unsigned short u16;
typedef __attribute__((ext_vector_type(8))) short bf16x8;   // 8 bf16 = 4 VGPR
typedef __attribute__((ext_vector_type(4))) short bf16x4;   // 4 bf16 = 2 VGPR
typedef __attribute__((ext_vector_type(4))) float f32x4;

#define D_MODEL 2048
#define SEQ     2048
#define NH      16
#define HD      128
#define BK      32

__device__ __forceinline__ u16 f2bf(float f){
  union { float f; unsigned u; } v; v.f = f;
  unsigned r = (v.u + 0x7FFFu + ((v.u >> 16) & 1u)) >> 16;  // RNE
  return (u16)r;
}

__device__ __forceinline__ void gll16(const void* g, void* l){
  __builtin_amdgcn_global_load_lds(
      (const __attribute__((address_space(1))) void*)g,
      (__attribute__((address_space(3))) void*)l, 16, 0, 0);
}

// ---------------- fp32 -> bf16 conversion of q,k,v ----------------
__global__ __launch_bounds__(256) void convert3_kernel(
    const float4* __restrict__ a, const float4* __restrict__ b, const float4* __restrict__ c,
    ushort4* __restrict__ oa, ushort4* __restrict__ ob, ushort4* __restrict__ oc){
  int i = blockIdx.x*256 + threadIdx.x;
  float4 va = a[i], vb = b[i], vc = c[i];
  ushort4 ra, rb, rc;
  ra.x=f2bf(va.x); ra.y=f2bf(va.y); ra.z=f2bf(va.z); ra.w=f2bf(va.w);
  rb.x=f2bf(vb.x); rb.y=f2bf(vb.y); rb.z=f2bf(vb.z); rb.w=f2bf(vb.w);
  rc.x=f2bf(vc.x); rc.y=f2bf(vc.y); rc.z=f2bf(vc.z); rc.w=f2bf(vc.w);
  oa[i]=ra; ob[i]=rb; oc[i]=rc;
}

// ---------------- transpose + convert: W[R][C] fp32 -> WT[C][R] bf16 ----------------
__global__ __launch_bounds__(256) void transpose_kernel(
    const float* __restrict__ in, u16* __restrict__ out, int R, int C){
  __shared__ float t[32][33];
  int c0 = blockIdx.x*32, r0 = blockIdx.y*32;
  int tx = threadIdx.x, ty = threadIdx.y;      // block (32,8)
  #pragma unroll
  for (int k=0;k<4;k++) t[ty+k*8][tx] = in[(size_t)(r0+ty+k*8)*C + c0+tx];
  __syncthreads();
  #pragma unroll
  for (int k=0;k<4;k++) out[(size_t)(c0+ty+k*8)*R + r0+tx] = f2bf(t[tx][ty+k*8]);
}

// ---------------- shared GEMM core (m97 structure) ----------------
__device__ __forceinline__ void gemm_core(
    const u16* __restrict__ A, const u16* __restrict__ BT,
    int lda, int ldb, int m0, int n0, int kbeg, int kend,
    u16* As, u16* Bs, f32x4 acc[4][4])
{
  const int t = threadIdx.x;
  const int w = t >> 6, l = t & 63;
  const int wr = w >> 1, wc = w & 1;
  const int c16 = l & 15, q = l >> 4;
  const int srow = l >> 2;
  const int sc   = ((l & 3) ^ ((l >> 3) & 3)) * 8;

  int aoff[4], boff[4];
  #pragma unroll
  for (int mt=0;mt<4;mt++){
    int row = wr*64 + mt*16 + c16;
    aoff[mt] = row*BK + ((q ^ ((row>>1)&3))*8);
  }
  #pragma unroll
  for (int nt=0;nt<4;nt++){
    int row = wc*64 + nt*16 + c16;
    boff[nt] = row*BK + ((q ^ ((row>>1)&3))*8);
  }

  for (int k0 = kbeg; k0 < kend; k0 += BK){
    #pragma unroll
    for (int half=0; half<2; half++){
      int r = half*64 + w*16 + srow;
      gll16(A  + (size_t)(m0+r)*lda + k0 + sc, As + (half*64 + w*16)*BK);
      gll16(BT + (size_t)(n0+r)*ldb + k0 + sc, Bs + (half*64 + w*16)*BK);
    }
    __syncthreads();
    bf16x8 af[4], bfr[4];
    #pragma unroll
    for (int mt=0;mt<4;mt++) af[mt]  = *(const bf16x8*)(As + aoff[mt]);
    #pragma unroll
    for (int nt=0;nt<4;nt++) bfr[nt] = *(const bf16x8*)(Bs + boff[nt]);
    #pragma unroll
    for (int mt=0;mt<4;mt++)
      #pragma unroll
      for (int nt=0;nt<4;nt++)
        acc[mt][nt] = __builtin_amdgcn_mfma_f32_16x16x32_bf16(af[mt], bfr[nt], acc[mt][nt], 0,0,0);
    __syncthreads();
  }
}

// ---------------- GEMM + bias, bf16 or fp32 output ----------------
template<bool BF16OUT>
__global__ __launch_bounds__(256) void gemm_bias(
    const u16* __restrict__ A, const u16* __restrict__ BT, const float* __restrict__ bias,
    void* __restrict__ C, int lda, int ldb, int ldc, int K)
{
  __shared__ u16 As[128*BK], Bs[128*BK];
  f32x4 acc[4][4];
  f32x4 z = {0.f,0.f,0.f,0.f};
  #pragma unroll
  for (int i=0;i<4;i++) for (int j=0;j<4;j++) acc[i][j] = z;
  int m0 = blockIdx.x*128, n0 = blockIdx.y*128;
  gemm_core(A, BT, lda, ldb, m0, n0, 0, K, As, Bs, acc);
  const int t = threadIdx.x, w = t>>6, l = t&63, wr = w>>1, wc = w&1, c16 = l&15, q = l>>4;
  #pragma unroll
  for (int mt=0;mt<4;mt++)
    #pragma unroll
    for (int nt=0;nt<4;nt++){
      int col = n0 + wc*64 + nt*16 + c16;
      float bv = bias[col];
      #pragma unroll
      for (int r=0;r<4;r++){
        int row = m0 + wr*64 + mt*16 + q*4 + r;
        float v = acc[mt][nt][r] + bv;
        if (BF16OUT) ((u16*)C)[(size_t)row*ldc + col] = f2bf(v);
        else         ((float*)C)[(size_t)row*ldc + col] = v;
      }
    }
}

// ---------------- fused K/V projection, split-K=4, fp32 partials ----------------
__global__ __launch_bounds__(256) void kvproj_kernel(
    const u16* __restrict__ kb, const u16* __restrict__ vb,
    const u16* __restrict__ WkT, const u16* __restrict__ WvT, float* __restrict__ part)
{
  __shared__ u16 As[128*BK], Bs[128*BK];
  f32x4 acc[4][4];
  f32x4 z = {0.f,0.f,0.f,0.f};
  #pragma unroll
  for (int i=0;i<4;i++) for (int j=0;j<4;j++) acc[i][j] = z;
  int m0 = blockIdx.x*128;
  int nb = blockIdx.y;
  int zi = blockIdx.z;
  const u16* A  = nb ? vb  : kb;
  const u16* BT = nb ? WvT : WkT;
  gemm_core(A, BT, D_MODEL, D_MODEL, m0, 0, zi*512, zi*512 + 512, As, Bs, acc);
  float* dst = part + (size_t)(zi*2 + nb)*524288;
  const int t = threadIdx.x, w = t>>6, l = t&63, wr = w>>1, wc = w&1, c16 = l&15, q = l>>4;
  #pragma unroll
  for (int mt=0;mt<4;mt++)
    #pragma unroll
    for (int nt=0;nt<4;nt++){
      int col = wc*64 + nt*16 + c16;
      #pragma unroll
      for (int r=0;r<4;r++){
        int row = m0 + wr*64 + mt*16 + q*4 + r;
        dst[(size_t)row*128 + col] = acc[mt][nt][r];
      }
    }
}

// ---------------- reduce split-K partials; Kp bf16 [4096][128], VpT bf16 [B][128][S] ----------------
__global__ __launch_bounds__(256) void kv_reduce_kernel(
    const float* __restrict__ part, const float* __restrict__ bk, const float* __restrict__ bv,
    u16* __restrict__ Kp, u16* __restrict__ VpT){
  int idx = blockIdx.x*256 + threadIdx.x;
  int d = idx & 127, sg = idx >> 7;
  float ka = 0.f, va = 0.f;
  #pragma unroll
  for (int zi=0; zi<4; zi++){
    ka += part[(size_t)(zi*2+0)*524288 + idx];
    va += part[(size_t)(zi*2+1)*524288 + idx];
  }
  Kp[idx] = f2bf(ka + bk[d]);
  int b = sg >> 11, sl = sg & 2047;
  VpT[(size_t)b*262144 + (size_t)d*2048 + sl] = f2bf(va + bv[d]);
}

// ---------------- flash attention (S^T formulation) ----------------
// Q-tile 128 rows (wave owns 32 = 2 sets of 16 q-columns), K-tile 128 keys.
// S^T = mfma(K,Q): lane holds q=c16, keys=quad*4+r -> softmax in-lane + 2 shuffles.
// P stays in registers as the 16x16x16 PV B-operand. O^T accumulates in C-layout.
// LDS 64 KB: Ks[128key][128d] | Vs[128d][128k], both chunk8-XOR-swizzled (2-way max).
__global__ __launch_bounds__(256) void attn_kernel(
    const u16* __restrict__ Qp, const u16* __restrict__ Kp,
    const u16* __restrict__ VpT, u16* __restrict__ attnb){
  __shared__ u16 lds[32768];
  u16* Ks = lds;
  u16* Vs = lds + 16384;
  const int t = threadIdx.x;
  const int w = t >> 6, l = t & 63;
  const int c16 = l & 15, q = l >> 4;

  const int qt = blockIdx.x;           // 0..15
  const int bh = blockIdx.y;           // 0..31
  const int b = bh >> 4, h = bh & 15;

  const u16* Qbase = Qp  + ((size_t)(b*SEQ + qt*128 + w*32))*D_MODEL + h*HD;
  const u16* Kbase = Kp  + (size_t)(b*SEQ)*HD;
  const u16* Vbase = VpT + (size_t)b*HD*SEQ;

  // stage this wave's 32 Q rows, then preload B-operand fragments to regs
  {
    u16* qtmp = lds + w*4096;
    #pragma unroll
    for (int j=0;j<8;j++){
      int r = j*4 + (l >> 4);
      int cpos = ((l & 15) ^ (r & 15)) * 8;
      gll16(Qbase + (size_t)r*D_MODEL + cpos, qtmp + j*512);
    }
  }
  __syncthreads();
  bf16x8 qf[2][4];
  #pragma unroll
  for (int qs=0;qs<2;qs++)
    #pragma unroll
    for (int kk=0;kk<4;kk++){
      int ch = kk*4 + q;
      qf[qs][kk] = *(const bf16x8*)(lds + w*4096 + (qs*16 + c16)*128 + ((ch ^ c16) & 15)*8);
    }
  __syncthreads();   // everyone done with Q scratch before K/V staging overwrites

  f32x4 o[2][8];
  f32x4 z4 = {0.f,0.f,0.f,0.f};
  #pragma unroll
  for (int qs=0;qs<2;qs++) for (int dt=0;dt<8;dt++) o[qs][dt] = z4;
  float mrow[2] = {-1e30f, -1e30f};
  float lrow[2] = {0.f, 0.f};
  const float cs = 0.08838834764831845f * 1.4426950408889634f;  // (1/sqrt(128))*log2(e)

  for (int kt = 0; kt < 16; kt++){
    // stage K tile: 128 keys x 128 d, chunk8 swizzle ^(key&15)
    #pragma unroll
    for (int j=0;j<8;j++){
      int r = j*16 + w*4 + (l >> 4);
      int g = (l & 15) ^ (r & 15);
      gll16(Kbase + (size_t)(kt*128 + r)*HD + g*8, Ks + j*2048 + w*512);
    }
    // stage V^T tile: 128 d x 128 k, chunk8 swizzle ^(d&15)
    #pragma unroll
    for (int j=0;j<8;j++){
      int d = j*16 + w*4 + (l >> 4);
      int g = (l & 15) ^ (d & 15);
      gll16(Vbase + (size_t)d*SEQ + kt*128 + g*8, Vs + j*2048 + w*512);
    }
    __syncthreads();

    // S^T = K Q^T : lane holds q-col=c16, key rows quad*4+r (+16*kt8)
    f32x4 s[2][8];
    #pragma unroll
    for (int qs=0;qs<2;qs++) for (int kt8=0;kt8<8;kt8++) s[qs][kt8] = z4;
    #pragma unroll
    for (int kt8=0; kt8<8; kt8++){
      #pragma unroll
      for (int kk=0;kk<4;kk++){
        int ch = kk*4 + q;
        bf16x8 kf = *(const bf16x8*)(Ks + (kt8*16 + c16)*128 + ((ch ^ c16) & 15)*8);
        s[0][kt8] = __builtin_amdgcn_mfma_f32_16x16x32_bf16(kf, qf[0][kk], s[0][kt8], 0,0,0);
        s[1][kt8] = __builtin_amdgcn_mfma_f32_16x16x32_bf16(kf, qf[1][kk], s[1][kt8], 0,0,0);
      }
    }

    // online softmax: all 32 in-lane values + 2 cross-quad shuffles per q-set
    float alpha[2];
    #pragma unroll
    for (int qs=0; qs<2; qs++){
      float vmax = s[qs][0][0];
      #pragma unroll
      for (int kt8=0;kt8<8;kt8++)
        #pragma unroll
        for (int r=0;r<4;r++) vmax = fmaxf(vmax, s[qs][kt8][r]);
      vmax = fmaxf(vmax, __shfl_xor(vmax, 16));
      vmax = fmaxf(vmax, __shfl_xor(vmax, 32));
      float mold = mrow[qs];
      float mnew = fmaxf(mold, vmax);
      float a = exp2f((mold - mnew)*cs);
      float mc = mnew*cs;
      float rsum = 0.f;
      #pragma unroll
      for (int kt8=0;kt8<8;kt8++)
        #pragma unroll
        for (int r=0;r<4;r++){
          float p = exp2f(__builtin_fmaf(s[qs][kt8][r], cs, -mc));
          s[qs][kt8][r] = p; rsum += p;
        }
      rsum += __shfl_xor(rsum, 16);
      rsum += __shfl_xor(rsum, 32);
      lrow[qs] = lrow[qs]*a + rsum;
      mrow[qs] = mnew;
      alpha[qs] = a;
    }
    // rescale O (skip when no lane's max moved — exact)
    unsigned long long allone = __ballot(alpha[0] == 1.f && alpha[1] == 1.f);
    if (allone != ~0ull){
      #pragma unroll
      for (int qs=0;qs<2;qs++)
        #pragma unroll
        for (int dt=0;dt<8;dt++)
          #pragma unroll
          for (int r=0;r<4;r++) o[qs][dt][r] *= alpha[qs];
    }

    // O^T += V^T P^T : A = V^T frag (LDS b64), B = P frag (registers)
    #pragma unroll
    for (int kt8=0; kt8<8; kt8++){
      bf16x4 p0, p1;
      #pragma unroll
      for (int j=0;j<4;j++){
        p0[j] = (short)f2bf(s[0][kt8][j]);
        p1[j] = (short)f2bf(s[1][kt8][j]);
      }
      #pragma unroll
      for (int dt=0; dt<8; dt++){
        int d = dt*16 + c16;
        int c4 = kt8*4 + q;
        int p8 = (c4 >> 1) ^ (d & 15);
        bf16x4 vf = *(const bf16x4*)(Vs + d*128 + p8*8 + (c4 & 1)*4);
        o[0][dt] = __builtin_amdgcn_mfma_f32_16x16x16bf16_1k(vf, p0, o[0][dt], 0,0,0);
        o[1][dt] = __builtin_amdgcn_mfma_f32_16x16x16bf16_1k(vf, p1, o[1][dt], 0,0,0);
      }
    }
    __syncthreads();
  }

  // normalize + write: lane holds O[q=c16+16qs][d=dt*16+quad*4+r] -> ushort4 along d
  #pragma unroll
  for (int qs=0;qs<2;qs++){
    float inv = 1.f / lrow[qs];
    int qrow = qt*128 + w*32 + qs*16 + c16;
    u16* dst = attnb + ((size_t)(b*SEQ) + qrow)*D_MODEL + h*HD + q*4;
    #pragma unroll
    for (int dt=0;dt<8;dt++){
      ushort4 pk;
      pk.x = f2bf(o[qs][dt][0]*inv);
      pk.y = f2bf(o[qs][dt][1]*inv);
      pk.z = f2bf(o[qs][dt][2]*inv);
      pk.w = f2bf(o[qs][dt][3]*inv);
      *(ushort4*)(dst + dt*16) = pk;
    }
  }
}

extern "C" void kernel_launch(void* const* d_in, const int* in_sizes, int n_in,
                              void* d_out, int out_size, void* d_ws, size_t ws_size,
                              hipStream_t stream) {
  (void)in_sizes; (void)n_in; (void)out_size; (void)ws_size;
  const float* query = (const float*)d_in[0];
  const float* key   = (const float*)d_in[1];
  const float* value = (const float*)d_in[2];
  const float* Wq    = (const float*)d_in[3];
  const float* bq    = (const float*)d_in[4];
  const float* Wk    = (const float*)d_in[5];
  const float* bk    = (const float*)d_in[6];
  const float* Wv    = (const float*)d_in[7];
  const float* bv    = (const float*)d_in[8];
  const float* Wo    = (const float*)d_in[9];
  const float* bo    = (const float*)d_in[10];
  float* out = (float*)d_out;

  char* W = (char*)d_ws;
  u16*  qb     = (u16*) (W + 0);          // 16 MB  bf16 query [4096][2048]
  u16*  kb     = (u16*) (W + 16777216);   // 16 MB  bf16 key
  u16*  vb     = (u16*) (W + 33554432);   // 16 MB  bf16 value
  u16*  WqT    = (u16*) (W + 50331648);   //  8 MB  Wq^T  [2048][2048]
  u16*  WoT    = (u16*) (W + 58720256);   //  8 MB  Wo^T
  u16*  WkT    = (u16*) (W + 67108864);   // .5 MB  Wk^T  [128][2048]
  u16*  WvT    = (u16*) (W + 67633152);   // .5 MB  Wv^T
  u16*  Qp     = (u16*) (W + 68157440);   // 16 MB  Q proj bf16 [4096][2048]
  u16*  Kp     = (u16*) (W + 84934656);   //  1 MB  K proj bf16 [4096][128]
  u16*  VpT    = (u16*) (W + 85983232);   //  1 MB  V proj^T bf16 [B][128][2048]
  u16*  attnb  = (u16*) (W + 87031808);   // 16 MB  attention out bf16 [4096][2048]
  float* kvpart= (float*)(W + 103809024); // 16 MB  split-K partials [4][2][4096][128]

  convert3_kernel<<<8192, 256, 0, stream>>>(
      (const float4*)query, (const float4*)key, (const float4*)value,
      (ushort4*)qb, (ushort4*)kb, (ushort4*)vb);
  transpose_kernel<<<dim3(64,64), dim3(32,8), 0, stream>>>(Wq, WqT, 2048, 2048);
  transpose_kernel<<<dim3(64,64), dim3(32,8), 0, stream>>>(Wo, WoT, 2048, 2048);
  transpose_kernel<<<dim3(4,64),  dim3(32,8), 0, stream>>>(Wk, WkT, 2048, 128);
  transpose_kernel<<<dim3(4,64),  dim3(32,8), 0, stream>>>(Wv, WvT, 2048, 128);

  gemm_bias<true><<<dim3(32,16), 256, 0, stream>>>(qb, WqT, bq, Qp, 2048, 2048, 2048, 2048);
  kvproj_kernel<<<dim3(32,2,4), 256, 0, stream>>>(kb, vb, WkT, WvT, kvpart);
  kv_reduce_kernel<<<2048, 256, 0, stream>>>(kvpart, bk, bv, Kp, VpT);
  attn_kernel<<<dim3(16,32), 256, 0, stream>>>(Qp, Kp, VpT, attnb);
  gemm_bias<false><<<dim3(32,16), 256, 0, stream>>>(attnb, WoT, bo, out, 2048, 2048, 2048, 2048);
}